// Round 14
// baseline (325.348 us; speedup 1.0000x reference)
//
#include <hip/hip_runtime.h>
#include <math.h>

// Problem constants: B=128,N=8 -> M=1024 rows; D=768; T=512; V=49408
#define VDIM    49408
#define NCH     193          // 49408 / 256 v-chunks
#define NSPLIT  16           // V splits; s = blockIdx&15 -> all 16 WGs of split on XCD s%8
#define NQT     16           // 1024 / 64 query tiles
#define NPROJ   256          // proj blocks FIRST (latency-bound, runs in prep's shadow)
#define NPREPB  772          // 64 rows per block: 2-tile (2x32-row) software pipeline

typedef __bf16 bf16;
typedef __bf16 bf16x8 __attribute__((ext_vector_type(8)));
typedef float  f32x4  __attribute__((ext_vector_type(4)));

// ---------------- Kernel AB (fused): proj (256 blocks) + prep (772 blocks) ---
// (round-13 version, frozen: 2-tile pipeline, register norm, 16-deep W dbuf)
__global__ __launch_bounds__(256) void k_pre(const float* __restrict__ emb,
        bf16* __restrict__ embS, bf16* __restrict__ embT, float* __restrict__ rs,
        const float* __restrict__ audio, const float* __restrict__ W,
        const float* __restrict__ bias, bf16* __restrict__ kwn,
        float4* __restrict__ zbase) {
    __shared__ __align__(16) unsigned char smem[32 * 512 * 2 + 32 * 4];
    const int tid = threadIdx.x;
    const int lane = tid & 63;

    if (blockIdx.x >= NPROJ) {
        // ===================== prep branch: 2 x 32-row tiles ================
        unsigned short* tile = (unsigned short*)smem;          // 32x512 bf16
        float* pnorm = (float*)(smem + 32 * 512 * 2);          // 32 floats
        const int b = blockIdx.x - NPROJ;                      // 0..771
        const int row = tid >> 3;          // 0..31
        const int c8  = tid & 7;           // col group within row
        const float4* srcb = (const float4*)(emb + (size_t)b * 64 * 512);

        // ---- tile 0: issue ALL 16 loads (deep MLP) ----
        float4 xb[16];
        #pragma unroll
        for (int j = 0; j < 16; ++j) xb[j] = srcb[row * 128 + c8 + j * 8];

        // ---- process tile 0: register norm partials + bf16 + swizzled LDS ----
        {
            float ss0 = 0.f, ss1 = 0.f;
            #pragma unroll
            for (int j = 0; j < 16; ++j) {
                const float4 x = xb[j];
                if (j & 1) ss1 = fmaf(x.x, x.x, fmaf(x.y, x.y, fmaf(x.z, x.z, fmaf(x.w, x.w, ss1))));
                else       ss0 = fmaf(x.x, x.x, fmaf(x.y, x.y, fmaf(x.z, x.z, fmaf(x.w, x.w, ss0))));
                const int c4 = c8 + j * 8;
                const int g = c4 >> 1, half = c4 & 1;
                ushort4 u;
                u.x = __builtin_bit_cast(unsigned short, (bf16)x.x);
                u.y = __builtin_bit_cast(unsigned short, (bf16)x.y);
                u.z = __builtin_bit_cast(unsigned short, (bf16)x.z);
                u.w = __builtin_bit_cast(unsigned short, (bf16)x.w);
                *(ushort4*)&tile[row * 512 + (((g ^ (row & 7)) << 3) + half * 4)] = u;
            }
            float ss = ss0 + ss1;
            ss += __shfl_xor(ss, 1);
            ss += __shfl_xor(ss, 2);
            ss += __shfl_xor(ss, 4);
            if (c8 == 0) pnorm[row] = ss;
        }

        // ---- issue tile-1 loads NOW: latency hides under tile-0 phase 2/3 ----
        float4 yb[16];
        #pragma unroll
        for (int j = 0; j < 16; ++j) yb[j] = srcb[4096 + row * 128 + c8 + j * 8];

        #pragma unroll
        for (int t = 0; t < 2; ++t) {
            const int bt = 2 * b + t;          // 32-row tile index (old b)
            __syncthreads();                   // tile stores + pnorm visible
            if (tid < 32)
                rs[bt * 32 + tid] = 10.0f / fmaxf(sqrtf(pnorm[tid]), 1e-8f);

            // phase 2: embS frag-major (uint4 LDS reads, coalesced writes)
            #pragma unroll
            for (int i = 0; i < 8; ++i) {
                const int F = i * 256 + tid;           // out granule 0..2047
                const int frag = F >> 6, l = F & 63;
                const int vt = frag >> 4, kf = frag & 15;   // vt 0..1
                const int lm = l & 15, lg = l >> 4;
                const int r = vt * 16 + lm, g = kf * 4 + lg;
                const uint4 d = *(const uint4*)&tile[r * 512 + ((g ^ (r & 7)) << 3)];
                *(uint4*)((unsigned short*)embS + ((size_t)(bt * 2 + vt) * 16 + kf) * 512 + l * 8) = d;
            }
            // phase 3: embT frag-major (transpose gather, coalesced writes)
            #pragma unroll
            for (int i = 0; i < 8; ++i) {
                const int F = i * 256 + tid;
                const int tt = F >> 6, l = F & 63;     // tt 0..31
                const int lm = l & 15, lg = l >> 4;
                const int tcol = tt * 16 + lm;
                unsigned short e[8];
                #pragma unroll
                for (int j = 0; j < 8; ++j) {
                    const int r = lg * 8 + j;          // 0..31
                    e[j] = tile[r * 512 + ((((tcol >> 3) ^ (r & 7)) << 3) + (tcol & 7))];
                }
                uint4 o;
                o.x = (unsigned)e[0] | ((unsigned)e[1] << 16);
                o.y = (unsigned)e[2] | ((unsigned)e[3] << 16);
                o.z = (unsigned)e[4] | ((unsigned)e[5] << 16);
                o.w = (unsigned)e[6] | ((unsigned)e[7] << 16);
                *(uint4*)((unsigned short*)embT + ((size_t)bt * 32 + tt) * 512 + l * 8) = o;
            }

            if (t == 0) {
                __syncthreads();               // tile-0 LDS reads complete
                // process tile 1 into LDS (yb already arrived under phase 2/3)
                float ss0 = 0.f, ss1 = 0.f;
                #pragma unroll
                for (int j = 0; j < 16; ++j) {
                    const float4 x = yb[j];
                    if (j & 1) ss1 = fmaf(x.x, x.x, fmaf(x.y, x.y, fmaf(x.z, x.z, fmaf(x.w, x.w, ss1))));
                    else       ss0 = fmaf(x.x, x.x, fmaf(x.y, x.y, fmaf(x.z, x.z, fmaf(x.w, x.w, ss0))));
                    const int c4 = c8 + j * 8;
                    const int g = c4 >> 1, half = c4 & 1;
                    ushort4 u;
                    u.x = __builtin_bit_cast(unsigned short, (bf16)x.x);
                    u.y = __builtin_bit_cast(unsigned short, (bf16)x.y);
                    u.z = __builtin_bit_cast(unsigned short, (bf16)x.z);
                    u.w = __builtin_bit_cast(unsigned short, (bf16)x.w);
                    *(ushort4*)&tile[row * 512 + (((g ^ (row & 7)) << 3) + half * 4)] = u;
                }
                float ss = ss0 + ss1;
                ss += __shfl_xor(ss, 1);
                ss += __shfl_xor(ss, 2);
                ss += __shfl_xor(ss, 4);
                if (c8 == 0) pnorm[row] = ss;
            }
        }
    } else {
        // ===================== proj branch (kw = audio@W + b, normalize) ====
        float* a_lds  = (float*)smem;                  // 4*768
        float* kw_lds = (float*)(smem + 12288);        // 4*512
        float* rn_lds = (float*)(smem + 20480);        // 4
        const int pb = blockIdx.x;
        const int q0 = pb * 4;

        // zero Oacc+Lsum slice (replaces hipMemsetAsync node): 513 float4/block
        for (int j = tid; j < 513; j += 256) zbase[pb * 513 + j] = float4{0.f, 0.f, 0.f, 0.f};

        const float4* asrc = (const float4*)(audio + q0 * 768);
        float4* adst = (float4*)a_lds;
        #pragma unroll
        for (int i = 0; i < 3; ++i) adst[i * 256 + tid] = asrc[i * 256 + tid];
        __syncthreads();

        // 16-deep register double-buffered W stream: 48 rounds, 32 loads in
        // flight while 128 FMAs execute -> latency covered, serial depth 48.
        float acc0[4] = {0.f, 0.f, 0.f, 0.f}, acc1[4] = {0.f, 0.f, 0.f, 0.f};
        float wa[16], wb[16];
        #pragma unroll
        for (int k = 0; k < 16; ++k) {
            wa[k] = W[k * 512 + tid];
            wb[k] = W[k * 512 + 256 + tid];
        }
        for (int dd = 0; dd < 48; ++dd) {
            float na[16], nb[16];
            if (dd < 47) {
                const int base = (dd + 1) * 16;
                #pragma unroll
                for (int k = 0; k < 16; ++k) {
                    na[k] = W[(base + k) * 512 + tid];
                    nb[k] = W[(base + k) * 512 + 256 + tid];
                }
            }
            #pragma unroll
            for (int k = 0; k < 16; ++k) {
                const int d = dd * 16 + k;
                #pragma unroll
                for (int q = 0; q < 4; ++q) {
                    const float a = a_lds[q * 768 + d];   // broadcast, conflict-free
                    acc0[q] = fmaf(a, wa[k], acc0[q]);
                    acc1[q] = fmaf(a, wb[k], acc1[q]);
                }
            }
            #pragma unroll
            for (int k = 0; k < 16; ++k) { wa[k] = na[k]; wb[k] = nb[k]; }
        }
        const float b0 = bias[tid], b1 = bias[256 + tid];
        #pragma unroll
        for (int q = 0; q < 4; ++q) {
            kw_lds[q * 512 + tid]       = acc0[q] + b0;
            kw_lds[q * 512 + 256 + tid] = acc1[q] + b1;
        }
        __syncthreads();

        const int w = tid >> 6;
        {   // wave w handles row w
            float ss = 0.f;
            #pragma unroll
            for (int i = 0; i < 8; ++i) { const float x = kw_lds[w * 512 + lane + i * 64]; ss = fmaf(x, x, ss); }
            #pragma unroll
            for (int o = 1; o < 64; o <<= 1) ss += __shfl_xor(ss, o);
            if (lane == 0) rn_lds[w] = 1.0f / fmaxf(sqrtf(ss), 1e-8f);
        }
        __syncthreads();
        #pragma unroll
        for (int i = 0; i < 8; ++i) {
            const int idx = i * 256 + tid;
            const int q = idx >> 9;
            kwn[(q0 + q) * 512 + (idx & 511)] = (bf16)(kw_lds[idx] * rn_lds[q]);
        }
    }
}

// ---------------- Kernel C: M64 producer/consumer fused attention ------------
// Base = round-10/13 measured-best (115.5-118us, MfmaUtil 39%): mfma(Q,E)
// producer, coarse flags, no setprio, full-loop releases. THIS round's single
// change: E-stream prefetch depth dist-2 -> dist-3 (4-buffer, static &3
// rotation) on BOTH producer embS and consumer embT. Arithmetic: per kf-iter
// compute covers ~310cy; dist-2 reach = 620cy < ~900cy L3/HBM first-touch ->
// ~300cy exposed x16 iters ~ 4.8k cy/chunk on the P critical path. dist-3
// reach = 930cy ~ full latency. (dist-1->dist-2 was +14us, prediction matched.)
__global__ __launch_bounds__(768, 3) void k_attn(const bf16* __restrict__ kwn,
        const bf16* __restrict__ embS, const bf16* __restrict__ embT,
        const float* __restrict__ rs, float* __restrict__ Oacc,
        float* __restrict__ Lsum) {
    __shared__ unsigned short Qlds[64 * 512];       // 64 KB, XOR-swizzled granules
    __shared__ unsigned short Plds[2 * 16384];      // 64 KB: 2 slots x (64q x 256v)
    __shared__ int prod_done[2], cons_done[2];
    const int tid = threadIdx.x;
    const int s = blockIdx.x & (NSPLIT - 1), qt = blockIdx.x >> 4;
    const int q0 = qt * 64;
    const int wg = tid >> 6, lane = tid & 63, lm = lane & 15, lg = lane >> 4;

    if (tid < 2) { prod_done[tid] = 0; cons_done[tid] = 0; }
    if (tid < 512) {   // stage Q tile (64x512 bf16), granule-swizzled g' = g^(q&7)
        const uint4* src = (const uint4*)(kwn + q0 * 512);
        #pragma unroll
        for (int i = 0; i < 8; ++i) {
            const int L = (i * 512 + tid) * 8;
            const int q = L >> 9, g = (L & 511) >> 3;
            *(uint4*)&Qlds[q * 512 + ((g ^ (q & 7)) << 3)] = src[i * 512 + tid];
        }
    }
    __syncthreads();   // covers Q staging + flag init

    const f32x4 zero4 = {0.f, 0.f, 0.f, 0.f};
    const int c0 = (s * NCH) / NSPLIT, c1 = ((s + 1) * NCH) / NSPLIT;
    const int n = c1 - c0;

    if (wg < 4) {
        // ================= producer: v-slice wg*64, all 64 q =================
        float lacc[4][4];
        #pragma unroll
        for (int mb = 0; mb < 4; ++mb)
            #pragma unroll
            for (int r = 0; r < 4; ++r) lacc[mb][r] = 0.f;
        for (int i = 0; i < n; ++i) {
            const int c = c0 + i;
            const int slot = i & 1, use = i >> 1;
            // rs preload: off the post-wait critical path (flag-independent)
            float rsv4[4];
            #pragma unroll
            for (int nb = 0; nb < 4; ++nb)
                rsv4[nb] = rs[c * 256 + wg * 64 + nb * 16 + lm];
            // ---- S compute (flag-independent), distance-3 4-buffer E stream ----
            f32x4 sacc[4][4];
            #pragma unroll
            for (int mb = 0; mb < 4; ++mb)
                #pragma unroll
                for (int nb = 0; nb < 4; ++nb) sacc[mb][nb] = zero4;
            const bf16* Eb = embS + ((size_t)(c * 16 + wg * 4) * 16) * 512 + lane * 8;
            bf16x8 eb[4][4];
            #pragma unroll
            for (int nb = 0; nb < 4; ++nb) {
                eb[0][nb] = *(const bf16x8*)(Eb + (nb * 16) * 512);
                eb[1][nb] = *(const bf16x8*)(Eb + (nb * 16 + 1) * 512);
                eb[2][nb] = *(const bf16x8*)(Eb + (nb * 16 + 2) * 512);
            }
            #pragma unroll
            for (int kf = 0; kf < 16; ++kf) {
                if (kf < 13) {     // distance-3 prefetch, static &3 rotation
                    #pragma unroll
                    for (int nb = 0; nb < 4; ++nb)
                        eb[(kf + 3) & 3][nb] = *(const bf16x8*)(Eb + (nb * 16 + kf + 3) * 512);
                }
                const int goff = ((kf * 4 + lg) ^ (lm & 7)) << 3;
                bf16x8 aq[4];
                #pragma unroll
                for (int mb = 0; mb < 4; ++mb)
                    aq[mb] = *(const bf16x8*)&Qlds[(mb * 16 + lm) * 512 + goff];
                #pragma unroll
                for (int nb = 0; nb < 4; ++nb)
                    #pragma unroll
                    for (int mb = 0; mb < 4; ++mb)
                        sacc[mb][nb] = __builtin_amdgcn_mfma_f32_16x16x32_bf16(aq[mb], eb[kf & 3][nb], sacc[mb][nb], 0, 0, 0);
                __builtin_amdgcn_sched_barrier(0);
            }
            // ---- wait slot free (8 consumers), then exp + scatter ----
            while (__hip_atomic_load(&cons_done[slot], __ATOMIC_ACQUIRE,
                                     __HIP_MEMORY_SCOPE_WORKGROUP) < 8 * use)
                __builtin_amdgcn_s_sleep(1);
            unsigned short* Pw = Plds + (slot << 14);
            #pragma unroll
            for (int nb = 0; nb < 4; ++nb) {
                const float rsv = rsv4[nb];
                const int kv = 2 * wg + (nb >> 1);
                const int lA = ((nb & 1) * 2 + (lm >> 3)) * 16;
                const int jj = lm & 7;
                #pragma unroll
                for (int mb = 0; mb < 4; ++mb) {
                    const int fragbase = (mb * 8 + kv) * 512;
                    #pragma unroll
                    for (int r = 0; r < 4; ++r) {
                        const float pv = __expf(sacc[mb][nb][r] * rsv);
                        const bf16 pb = (bf16)pv;
                        lacc[mb][r] += (float)pb;   // rounded value for consistency
                        const int ldest = lA + lg * 4 + r;
                        Pw[fragbase + ldest * 8 + jj] = __builtin_bit_cast(unsigned short, pb);
                    }
                }
            }
            if (lane == 0)   // ONE increment per wave (release drains LDS writes)
                __hip_atomic_fetch_add(&prod_done[slot], 1, __ATOMIC_RELEASE,
                                       __HIP_MEMORY_SCOPE_WORKGROUP);
        }
        // Lsum: partial over this wave's v-slices, one atomic per q at the end
        #pragma unroll
        for (int mb = 0; mb < 4; ++mb)
            #pragma unroll
            for (int r = 0; r < 4; ++r) {
                float sum = lacc[mb][r];
                sum += __shfl_xor(sum, 1);
                sum += __shfl_xor(sum, 2);
                sum += __shfl_xor(sum, 4);
                sum += __shfl_xor(sum, 8);
                if (lm == 0) atomicAdd(&Lsum[q0 + mb * 16 + lg * 4 + r], sum);
            }
    } else {
        // ================= consumer: t-slice (wg-4)*64, all 64 q =============
        const int cw = wg - 4;
        f32x4 acc[4][4];                   // [mb 16q][nt 16t]
        #pragma unroll
        for (int mb = 0; mb < 4; ++mb)
            #pragma unroll
            for (int nt = 0; nt < 4; ++nt) acc[mb][nt] = zero4;
        for (int i = 0; i < n; ++i) {
            const int cc = c0 + i;
            const int slot = i & 1, use = i >> 1;
            const bf16* ETb = embT + ((size_t)cc * 256 + cw * 4) * 512 + lane * 8;
            // distance-3 4-buffer ET stream; kf=0,1,2 issued BEFORE the flag wait
            bf16x8 et[4][4];
            #pragma unroll
            for (int nt = 0; nt < 4; ++nt) {
                et[0][nt] = *(const bf16x8*)(ETb + nt * 512);
                et[1][nt] = *(const bf16x8*)(ETb + (32 + nt) * 512);
                et[2][nt] = *(const bf16x8*)(ETb + (64 + nt) * 512);
            }
            while (__hip_atomic_load(&prod_done[slot], __ATOMIC_ACQUIRE,
                                     __HIP_MEMORY_SCOPE_WORKGROUP) < 4 * (use + 1))
                __builtin_amdgcn_s_sleep(1);
            const unsigned short* Pb = Plds + (slot << 14);
            #pragma unroll
            for (int kf = 0; kf < 8; ++kf) {
                if (kf < 5) {      // distance-3 prefetch, static &3 rotation
                    #pragma unroll
                    for (int nt = 0; nt < 4; ++nt)
                        et[(kf + 3) & 3][nt] = *(const bf16x8*)(ETb + ((kf + 3) * 32 + nt) * 512);
                }
                bf16x8 pf[4];
                #pragma unroll
                for (int mb = 0; mb < 4; ++mb)
                    pf[mb] = *(const bf16x8*)&Pb[(mb * 8 + kf) * 512 + lane * 8];
                #pragma unroll
                for (int nt = 0; nt < 4; ++nt)
                    #pragma unroll
                    for (int mb = 0; mb < 4; ++mb)
                        acc[mb][nt] = __builtin_amdgcn_mfma_f32_16x16x32_bf16(pf[mb], et[kf & 3][nt], acc[mb][nt], 0, 0, 0);
                __builtin_amdgcn_sched_barrier(0);
            }
            if (lane == 0)   // ONE increment per wave (release drains LDS reads)
                __hip_atomic_fetch_add(&cons_done[slot], 1, __ATOMIC_RELEASE,
                                       __HIP_MEMORY_SCOPE_WORKGROUP);
        }
        // epilogue: combine partials across v-splits
        #pragma unroll
        for (int mb = 0; mb < 4; ++mb)
            #pragma unroll
            for (int nt = 0; nt < 4; ++nt)
                #pragma unroll
                for (int r = 0; r < 4; ++r) {
                    const int q = q0 + mb * 16 + lg * 4 + r;
                    const int t = cw * 64 + nt * 16 + lm;
                    atomicAdd(&Oacc[q * 512 + t], acc[mb][nt][r]);
                }
    }
}

// ---------------- Kernel D: out = Oacc / Lsum --------------------------------
__global__ __launch_bounds__(256) void k_final(const float* __restrict__ Oacc,
        const float* __restrict__ Lsum, float* __restrict__ out) {
    const int i = blockIdx.x * 256 + threadIdx.x;   // float4 index, 131072 total
    const float4 o = ((const float4*)Oacc)[i];
    const float inv = 1.0f / Lsum[i >> 7];          // 128 float4 per row
    float4 r;
    r.x = o.x * inv; r.y = o.y * inv; r.z = o.z * inv; r.w = o.w * inv;
    ((float4*)out)[i] = r;
}

// ---------------- launcher ---------------------------------------------------
// ws layout (bytes) — total 104,535,040 (proven to fit):
//   0        kwn   bf16 [1024*512]          1,048,576
//   1048576  rs    f32  [49408]               197,632
//   1246208  Oacc  f32  [1024*512]          2,097,152   (zeroed by k_pre proj blocks)
//   3343360  Lsum  f32  [1024]                   4,096   (zeroed by k_pre proj blocks)
//   3347456  embS  bf16 frag-major          50,593,792
//   53941248 embT  bf16 frag-major          50,593,792
extern "C" void kernel_launch(void* const* d_in, const int* in_sizes, int n_in,
                              void* d_out, int out_size, void* d_ws, size_t ws_size,
                              hipStream_t stream) {
    const float* audio = (const float*)d_in[0];
    const float* W     = (const float*)d_in[1];
    const float* bias  = (const float*)d_in[2];
    const float* emb   = (const float*)d_in[3];
    float* out = (float*)d_out;
    char* ws = (char*)d_ws;

    bf16*  kwn  = (bf16*)(ws);
    float* rs   = (float*)(ws + 1048576);
    float* Oacc = (float*)(ws + 1246208);
    float* Lsum = (float*)(ws + 3343360);
    bf16*  embS = (bf16*)(ws + 3347456);
    bf16*  embT = (bf16*)(ws + 53941248);
    float4* zbase = (float4*)(ws + 1246208);        // Oacc+Lsum contiguous, 131328 float4

    k_pre<<<NPROJ + NPREPB, 256, 0, stream>>>(emb, embS, embT, rs, audio, W, bias, kwn, zbase);
    k_attn<<<NQT * NSPLIT, 768, 0, stream>>>(kwn, embS, embT, rs, Oacc, Lsum);
    k_final<<<(out_size / 4) / 256, 256, 0, stream>>>(Oacc, Lsum, out);
}

// Round 15
// 310.307 us; speedup vs baseline: 1.0485x; 1.0485x over previous
//
#include <hip/hip_runtime.h>
#include <math.h>

// Problem constants: B=128,N=8 -> M=1024 rows; D=768; T=512; V=49408
#define VDIM    49408
#define NCH     193          // 49408 / 256 v-chunks
#define NSPLIT  16           // V splits; s = blockIdx&15 -> all 16 WGs of split on XCD s%8
#define NQT     16           // 1024 / 64 query tiles
#define NPROJ   256          // proj blocks FIRST (latency-bound, runs in prep's shadow)
#define NPREPB  1544         // VDIM/32 prep blocks (32-row tiles)

typedef __bf16 bf16;
typedef __bf16 bf16x8 __attribute__((ext_vector_type(8)));
typedef float  f32x4  __attribute__((ext_vector_type(4)));

// ---------------- Kernel AB (fused): proj (256 blocks) + prep (1544 blocks) --
// (round-9/10 version, frozen: row-per-thread-group register norm, 16-deep W dbuf)
__global__ __launch_bounds__(256) void k_pre(const float* __restrict__ emb,
        bf16* __restrict__ embS, bf16* __restrict__ embT, float* __restrict__ rs,
        const float* __restrict__ audio, const float* __restrict__ W,
        const float* __restrict__ bias, bf16* __restrict__ kwn,
        float4* __restrict__ zbase) {
    __shared__ __align__(16) unsigned char smem[32 * 512 * 2 + 32 * 4];
    const int tid = threadIdx.x;
    const int lane = tid & 63;

    if (blockIdx.x >= NPROJ) {
        // ===================== prep branch: 32-row tile =====================
        unsigned short* tile = (unsigned short*)smem;          // 32x512 bf16
        float* pnorm = (float*)(smem + 32 * 512 * 2);          // 32 floats
        const int b = blockIdx.x - NPROJ;
        const int v0 = b * 32;

        // 1: row-per-thread-group loads (8 threads/row, 16 float4 each),
        //    per-lane register norm partials, bf16 convert + swizzled LDS store.
        const float4* src = (const float4*)(emb + (size_t)v0 * 512);
        const int row = tid >> 3;          // 0..31
        const int c8  = tid & 7;           // col group within row
        float ss0 = 0.f, ss1 = 0.f;
        #pragma unroll
        for (int ii = 0; ii < 2; ++ii) {
            float4 xb[8];
            #pragma unroll
            for (int j = 0; j < 8; ++j)
                xb[j] = src[row * 128 + c8 + (ii * 8 + j) * 8];
            #pragma unroll
            for (int j = 0; j < 8; ++j) {
                const float4 x = xb[j];
                if (j & 1) ss1 = fmaf(x.x, x.x, fmaf(x.y, x.y, fmaf(x.z, x.z, fmaf(x.w, x.w, ss1))));
                else       ss0 = fmaf(x.x, x.x, fmaf(x.y, x.y, fmaf(x.z, x.z, fmaf(x.w, x.w, ss0))));
                const int c4 = c8 + (ii * 8 + j) * 8;
                const int g = c4 >> 1, half = c4 & 1;
                ushort4 u;
                u.x = __builtin_bit_cast(unsigned short, (bf16)x.x);
                u.y = __builtin_bit_cast(unsigned short, (bf16)x.y);
                u.z = __builtin_bit_cast(unsigned short, (bf16)x.z);
                u.w = __builtin_bit_cast(unsigned short, (bf16)x.w);
                *(ushort4*)&tile[row * 512 + (((g ^ (row & 7)) << 3) + half * 4)] = u;
            }
        }
        {   // 8-lane reduce per row (rows are lane-aligned groups of 8)
            float ss = ss0 + ss1;
            ss += __shfl_xor(ss, 1);
            ss += __shfl_xor(ss, 2);
            ss += __shfl_xor(ss, 4);
            if (c8 == 0) pnorm[row] = ss;
        }
        __syncthreads();
        if (tid < 32)
            rs[v0 + tid] = 10.0f / fmaxf(sqrtf(pnorm[tid]), 1e-8f);   // folds 1/TEMP

        // 2: embS frag-major (uint4 LDS reads, coalesced global writes), 8 iters
        #pragma unroll
        for (int i = 0; i < 8; ++i) {
            const int F = i * 256 + tid;           // out granule 0..2047
            const int frag = F >> 6, l = F & 63;
            const int vt = frag >> 4, kf = frag & 15;   // vt 0..1
            const int lm = l & 15, lg = l >> 4;
            const int r = vt * 16 + lm, g = kf * 4 + lg;
            const uint4 d = *(const uint4*)&tile[r * 512 + ((g ^ (r & 7)) << 3)];
            *(uint4*)((unsigned short*)embS + ((size_t)(b * 2 + vt) * 16 + kf) * 512 + l * 8) = d;
        }
        // 3: embT frag-major (transpose gather from LDS, coalesced writes), 8 iters
        #pragma unroll
        for (int i = 0; i < 8; ++i) {
            const int F = i * 256 + tid;
            const int tt = F >> 6, l = F & 63;     // tt 0..31
            const int lm = l & 15, lg = l >> 4;
            const int t = tt * 16 + lm;
            unsigned short e[8];
            #pragma unroll
            for (int j = 0; j < 8; ++j) {
                const int r = lg * 8 + j;          // 0..31
                e[j] = tile[r * 512 + ((((t >> 3) ^ (r & 7)) << 3) + (t & 7))];
            }
            uint4 o;
            o.x = (unsigned)e[0] | ((unsigned)e[1] << 16);
            o.y = (unsigned)e[2] | ((unsigned)e[3] << 16);
            o.z = (unsigned)e[4] | ((unsigned)e[5] << 16);
            o.w = (unsigned)e[6] | ((unsigned)e[7] << 16);
            *(uint4*)((unsigned short*)embT + ((size_t)b * 32 + tt) * 512 + l * 8) = o;
        }
    } else {
        // ===================== proj branch (kw = audio@W + b, normalize) ====
        float* a_lds  = (float*)smem;                  // 4*768
        float* kw_lds = (float*)(smem + 12288);        // 4*512
        float* rn_lds = (float*)(smem + 20480);        // 4
        const int pb = blockIdx.x;
        const int q0 = pb * 4;

        // zero Oacc+Lsum slice (replaces hipMemsetAsync node): 513 float4/block
        for (int j = tid; j < 513; j += 256) zbase[pb * 513 + j] = float4{0.f, 0.f, 0.f, 0.f};

        const float4* asrc = (const float4*)(audio + q0 * 768);
        float4* adst = (float4*)a_lds;
        #pragma unroll
        for (int i = 0; i < 3; ++i) adst[i * 256 + tid] = asrc[i * 256 + tid];
        __syncthreads();

        // 16-deep register double-buffered W stream: 48 rounds, 32 loads in
        // flight while 128 FMAs execute -> latency covered, serial depth 48.
        float acc0[4] = {0.f, 0.f, 0.f, 0.f}, acc1[4] = {0.f, 0.f, 0.f, 0.f};
        float wa[16], wb[16];
        #pragma unroll
        for (int k = 0; k < 16; ++k) {
            wa[k] = W[k * 512 + tid];
            wb[k] = W[k * 512 + 256 + tid];
        }
        for (int dd = 0; dd < 48; ++dd) {
            float na[16], nb[16];
            if (dd < 47) {
                const int base = (dd + 1) * 16;
                #pragma unroll
                for (int k = 0; k < 16; ++k) {
                    na[k] = W[(base + k) * 512 + tid];
                    nb[k] = W[(base + k) * 512 + 256 + tid];
                }
            }
            #pragma unroll
            for (int k = 0; k < 16; ++k) {
                const int d = dd * 16 + k;
                #pragma unroll
                for (int q = 0; q < 4; ++q) {
                    const float a = a_lds[q * 768 + d];   // broadcast, conflict-free
                    acc0[q] = fmaf(a, wa[k], acc0[q]);
                    acc1[q] = fmaf(a, wb[k], acc1[q]);
                }
            }
            #pragma unroll
            for (int k = 0; k < 16; ++k) { wa[k] = na[k]; wb[k] = nb[k]; }
        }
        const float b0 = bias[tid], b1 = bias[256 + tid];
        #pragma unroll
        for (int q = 0; q < 4; ++q) {
            kw_lds[q * 512 + tid]       = acc0[q] + b0;
            kw_lds[q * 512 + 256 + tid] = acc1[q] + b1;
        }
        __syncthreads();

        const int w = tid >> 6;
        {   // wave w handles row w
            float ss = 0.f;
            #pragma unroll
            for (int i = 0; i < 8; ++i) { const float x = kw_lds[w * 512 + lane + i * 64]; ss = fmaf(x, x, ss); }
            #pragma unroll
            for (int o = 1; o < 64; o <<= 1) ss += __shfl_xor(ss, o);
            if (lane == 0) rn_lds[w] = 1.0f / fmaxf(sqrtf(ss), 1e-8f);
        }
        __syncthreads();
        #pragma unroll
        for (int i = 0; i < 8; ++i) {
            const int idx = i * 256 + tid;
            const int q = idx >> 9;
            kwn[(q0 + q) * 512 + (idx & 511)] = (bf16)(kw_lds[idx] * rn_lds[q]);
        }
    }
}

// ---------------- Kernel C: M64 producer/consumer fused attention ------------
// FINAL = round-10 measured-best (115.5us, MfmaUtil 39.4%): mfma(Q,E) producer,
// b16 scatter, scalar rs hoist, coarse flags, no setprio, full-loop releases,
// dist-2 3-buffer E streams. Retired levers (each double-measured negative):
// setprio/early-release (117->137), operand-swap (115->123 twice), dist-3
// (118->139: compiler sinks loads past dist-2 and demotes the 4th buffer to
// scratch — WRITE_SIZE +17.6MB at pinned VGPR=84).
__global__ __launch_bounds__(768, 3) void k_attn(const bf16* __restrict__ kwn,
        const bf16* __restrict__ embS, const bf16* __restrict__ embT,
        const float* __restrict__ rs, float* __restrict__ Oacc,
        float* __restrict__ Lsum) {
    __shared__ unsigned short Qlds[64 * 512];       // 64 KB, XOR-swizzled granules
    __shared__ unsigned short Plds[2 * 16384];      // 64 KB: 2 slots x (64q x 256v)
    __shared__ int prod_done[2], cons_done[2];
    const int tid = threadIdx.x;
    const int s = blockIdx.x & (NSPLIT - 1), qt = blockIdx.x >> 4;
    const int q0 = qt * 64;
    const int wg = tid >> 6, lane = tid & 63, lm = lane & 15, lg = lane >> 4;

    if (tid < 2) { prod_done[tid] = 0; cons_done[tid] = 0; }
    if (tid < 512) {   // stage Q tile (64x512 bf16), granule-swizzled g' = g^(q&7)
        const uint4* src = (const uint4*)(kwn + q0 * 512);
        #pragma unroll
        for (int i = 0; i < 8; ++i) {
            const int L = (i * 512 + tid) * 8;
            const int q = L >> 9, g = (L & 511) >> 3;
            *(uint4*)&Qlds[q * 512 + ((g ^ (q & 7)) << 3)] = src[i * 512 + tid];
        }
    }
    __syncthreads();   // covers Q staging + flag init

    const f32x4 zero4 = {0.f, 0.f, 0.f, 0.f};
    const int c0 = (s * NCH) / NSPLIT, c1 = ((s + 1) * NCH) / NSPLIT;
    const int n = c1 - c0;

    if (wg < 4) {
        // ================= producer: v-slice wg*64, all 64 q =================
        float lacc[4][4];
        #pragma unroll
        for (int mb = 0; mb < 4; ++mb)
            #pragma unroll
            for (int r = 0; r < 4; ++r) lacc[mb][r] = 0.f;
        for (int i = 0; i < n; ++i) {
            const int c = c0 + i;
            const int slot = i & 1, use = i >> 1;
            // rs preload: off the post-wait critical path (flag-independent)
            float rsv4[4];
            #pragma unroll
            for (int nb = 0; nb < 4; ++nb)
                rsv4[nb] = rs[c * 256 + wg * 64 + nb * 16 + lm];
            // ---- S compute (flag-independent), distance-2 3-buffer E stream ----
            f32x4 sacc[4][4];
            #pragma unroll
            for (int mb = 0; mb < 4; ++mb)
                #pragma unroll
                for (int nb = 0; nb < 4; ++nb) sacc[mb][nb] = zero4;
            const bf16* Eb = embS + ((size_t)(c * 16 + wg * 4) * 16) * 512 + lane * 8;
            bf16x8 eb[3][4];
            #pragma unroll
            for (int nb = 0; nb < 4; ++nb) {
                eb[0][nb] = *(const bf16x8*)(Eb + (nb * 16) * 512);
                eb[1][nb] = *(const bf16x8*)(Eb + (nb * 16 + 1) * 512);
            }
            #pragma unroll
            for (int kf = 0; kf < 16; ++kf) {
                if (kf < 14) {     // distance-2 prefetch, static %3 rotation
                    #pragma unroll
                    for (int nb = 0; nb < 4; ++nb)
                        eb[(kf + 2) % 3][nb] = *(const bf16x8*)(Eb + (nb * 16 + kf + 2) * 512);
                }
                const int goff = ((kf * 4 + lg) ^ (lm & 7)) << 3;
                bf16x8 aq[4];
                #pragma unroll
                for (int mb = 0; mb < 4; ++mb)
                    aq[mb] = *(const bf16x8*)&Qlds[(mb * 16 + lm) * 512 + goff];
                #pragma unroll
                for (int nb = 0; nb < 4; ++nb)
                    #pragma unroll
                    for (int mb = 0; mb < 4; ++mb)
                        sacc[mb][nb] = __builtin_amdgcn_mfma_f32_16x16x32_bf16(aq[mb], eb[kf % 3][nb], sacc[mb][nb], 0, 0, 0);
                __builtin_amdgcn_sched_barrier(0);
            }
            // ---- wait slot free (8 consumers), then exp + scatter ----
            while (__hip_atomic_load(&cons_done[slot], __ATOMIC_ACQUIRE,
                                     __HIP_MEMORY_SCOPE_WORKGROUP) < 8 * use)
                __builtin_amdgcn_s_sleep(1);
            unsigned short* Pw = Plds + (slot << 14);
            #pragma unroll
            for (int nb = 0; nb < 4; ++nb) {
                const float rsv = rsv4[nb];
                const int kv = 2 * wg + (nb >> 1);
                const int lA = ((nb & 1) * 2 + (lm >> 3)) * 16;
                const int jj = lm & 7;
                #pragma unroll
                for (int mb = 0; mb < 4; ++mb) {
                    const int fragbase = (mb * 8 + kv) * 512;
                    #pragma unroll
                    for (int r = 0; r < 4; ++r) {
                        const float pv = __expf(sacc[mb][nb][r] * rsv);
                        const bf16 pb = (bf16)pv;
                        lacc[mb][r] += (float)pb;   // rounded value for consistency
                        const int ldest = lA + lg * 4 + r;
                        Pw[fragbase + ldest * 8 + jj] = __builtin_bit_cast(unsigned short, pb);
                    }
                }
            }
            if (lane == 0)   // ONE increment per wave (release drains LDS writes)
                __hip_atomic_fetch_add(&prod_done[slot], 1, __ATOMIC_RELEASE,
                                       __HIP_MEMORY_SCOPE_WORKGROUP);
        }
        // Lsum: partial over this wave's v-slices, one atomic per q at the end
        #pragma unroll
        for (int mb = 0; mb < 4; ++mb)
            #pragma unroll
            for (int r = 0; r < 4; ++r) {
                float sum = lacc[mb][r];
                sum += __shfl_xor(sum, 1);
                sum += __shfl_xor(sum, 2);
                sum += __shfl_xor(sum, 4);
                sum += __shfl_xor(sum, 8);
                if (lm == 0) atomicAdd(&Lsum[q0 + mb * 16 + lg * 4 + r], sum);
            }
    } else {
        // ================= consumer: t-slice (wg-4)*64, all 64 q =============
        const int cw = wg - 4;
        f32x4 acc[4][4];                   // [mb 16q][nt 16t]
        #pragma unroll
        for (int mb = 0; mb < 4; ++mb)
            #pragma unroll
            for (int nt = 0; nt < 4; ++nt) acc[mb][nt] = zero4;
        for (int i = 0; i < n; ++i) {
            const int cc = c0 + i;
            const int slot = i & 1, use = i >> 1;
            const bf16* ETb = embT + ((size_t)cc * 256 + cw * 4) * 512 + lane * 8;
            // distance-2 3-buffer ET stream; kf=0,1 issued BEFORE the flag wait
            bf16x8 et[3][4];
            #pragma unroll
            for (int nt = 0; nt < 4; ++nt) {
                et[0][nt] = *(const bf16x8*)(ETb + nt * 512);
                et[1][nt] = *(const bf16x8*)(ETb + (32 + nt) * 512);
            }
            while (__hip_atomic_load(&prod_done[slot], __ATOMIC_ACQUIRE,
                                     __HIP_MEMORY_SCOPE_WORKGROUP) < 4 * (use + 1))
                __builtin_amdgcn_s_sleep(1);
            const unsigned short* Pb = Plds + (slot << 14);
            #pragma unroll
            for (int kf = 0; kf < 8; ++kf) {
                if (kf < 6) {      // distance-2 prefetch, static %3 rotation
                    #pragma unroll
                    for (int nt = 0; nt < 4; ++nt)
                        et[(kf + 2) % 3][nt] = *(const bf16x8*)(ETb + ((kf + 2) * 32 + nt) * 512);
                }
                bf16x8 pf[4];
                #pragma unroll
                for (int mb = 0; mb < 4; ++mb)
                    pf[mb] = *(const bf16x8*)&Pb[(mb * 8 + kf) * 512 + lane * 8];
                #pragma unroll
                for (int nt = 0; nt < 4; ++nt)
                    #pragma unroll
                    for (int mb = 0; mb < 4; ++mb)
                        acc[mb][nt] = __builtin_amdgcn_mfma_f32_16x16x32_bf16(pf[mb], et[kf % 3][nt], acc[mb][nt], 0, 0, 0);
                __builtin_amdgcn_sched_barrier(0);
            }
            if (lane == 0)   // ONE increment per wave (release drains LDS reads)
                __hip_atomic_fetch_add(&cons_done[slot], 1, __ATOMIC_RELEASE,
                                       __HIP_MEMORY_SCOPE_WORKGROUP);
        }
        // epilogue: combine partials across v-splits
        #pragma unroll
        for (int mb = 0; mb < 4; ++mb)
            #pragma unroll
            for (int nt = 0; nt < 4; ++nt)
                #pragma unroll
                for (int r = 0; r < 4; ++r) {
                    const int q = q0 + mb * 16 + lg * 4 + r;
                    const int t = cw * 64 + nt * 16 + lm;
                    atomicAdd(&Oacc[q * 512 + t], acc[mb][nt][r]);
                }
    }
}

// ---------------- Kernel D: out = Oacc / Lsum --------------------------------
__global__ __launch_bounds__(256) void k_final(const float* __restrict__ Oacc,
        const float* __restrict__ Lsum, float* __restrict__ out) {
    const int i = blockIdx.x * 256 + threadIdx.x;   // float4 index, 131072 total
    const float4 o = ((const float4*)Oacc)[i];
    const float inv = 1.0f / Lsum[i >> 7];          // 128 float4 per row
    float4 r;
    r.x = o.x * inv; r.y = o.y * inv; r.z = o.z * inv; r.w = o.w * inv;
    ((float4*)out)[i] = r;
}

// ---------------- launcher ---------------------------------------------------
// ws layout (bytes) — total 104,535,040 (proven to fit):
//   0        kwn   bf16 [1024*512]          1,048,576
//   1048576  rs    f32  [49408]               197,632
//   1246208  Oacc  f32  [1024*512]          2,097,152   (zeroed by k_pre proj blocks)
//   3343360  Lsum  f32  [1024]                   4,096   (zeroed by k_pre proj blocks)
//   3347456  embS  bf16 frag-major          50,593,792
//   53941248 embT  bf16 frag-major          50,593,792
extern "C" void kernel_launch(void* const* d_in, const int* in_sizes, int n_in,
                              void* d_out, int out_size, void* d_ws, size_t ws_size,
                              hipStream_t stream) {
    const float* audio = (const float*)d_in[0];
    const float* W     = (const float*)d_in[1];
    const float* bias  = (const float*)d_in[2];
    const float* emb   = (const float*)d_in[3];
    float* out = (float*)d_out;
    char* ws = (char*)d_ws;

    bf16*  kwn  = (bf16*)(ws);
    float* rs   = (float*)(ws + 1048576);
    float* Oacc = (float*)(ws + 1246208);
    float* Lsum = (float*)(ws + 3343360);
    bf16*  embS = (bf16*)(ws + 3347456);
    bf16*  embT = (bf16*)(ws + 53941248);
    float4* zbase = (float4*)(ws + 1246208);        // Oacc+Lsum contiguous, 131328 float4

    k_pre<<<NPROJ + NPREPB, 256, 0, stream>>>(emb, embS, embT, rs, audio, W, bias, kwn, zbase);
    k_attn<<<NQT * NSPLIT, 768, 0, stream>>>(kwn, embS, embT, rs, Oacc, Lsum);
    k_final<<<(out_size / 4) / 256, 256, 0, stream>>>(Oacc, Lsum, out);
}